// Round 1
// baseline (424.070 us; speedup 1.0000x reference)
//
#include <hip/hip_runtime.h>
#include <cstdint>
#include <cstddef>

// B=2,S=1024 -> T=2048 tokens
#define T_TOK 2048
#define HDIM  1024
#define IDIM  2048
#define NEXP  8

#define BM 128
#define BK1 32          // gemm1 K-tile
#define BK2 64          // gemm2 K-tile
#define BN2 64          // gemm2 col tile
#define MAXPAD 3072
#define SH_TILES 16     // T_TOK/BM
#define RT_TILES 24     // MAXPAD/BM

typedef __attribute__((ext_vector_type(8))) short short8;
typedef __attribute__((ext_vector_type(4))) short short4v;
typedef __attribute__((ext_vector_type(4))) float float4v;

__device__ __forceinline__ short f2bf(float f) {
  uint32_t u = __float_as_uint(f);
  u += 0x7fffu + ((u >> 16) & 1u);
  return (short)(u >> 16);
}

__device__ __forceinline__ void gload_lds16(const void* g, void* l) {
  __builtin_amdgcn_global_load_lds(
      (const __attribute__((address_space(1))) uint32_t*)g,
      (__attribute__((address_space(3))) uint32_t*)l, 16, 0, 0);
}

// 16B-chunk XOR swizzles (self-inverse). Staged with linear LDS dest +
// swizzled global source; fragment reads apply the same swizzle (rule #21).
// BK=32 rows = 4 chunks: bits[1:0] ^= bits[5:4]
__device__ __forceinline__ int swz(int c) { return c ^ ((c >> 4) & 3); }
// BK=64 rows = 8 chunks: bits[2:0] ^= bits[5:3]
__device__ __forceinline__ int swz64(int c) { return c ^ ((c >> 3) & 7); }

// ---------------------------------------------------------------- small kernels

__global__ __launch_bounds__(256) void zero_init(int* __restrict__ counts,
                                                 int* __restrict__ perm) {
  int i = threadIdx.x;
  if (i < NEXP) counts[i] = 0;
  for (int p = i; p < MAXPAD; p += 256) perm[p] = 0;
}

// one wave per token: fp32 logits (exact argmax vs ref), score, bf16 copies
__global__ __launch_bounds__(256) void router_kernel(
    const float* __restrict__ x, const float* __restrict__ gw,
    short* __restrict__ xbf, short* __restrict__ xsbf,
    int* __restrict__ expert_id, int* __restrict__ slot,
    int* __restrict__ counts) {
  int wv = threadIdx.x >> 6, lane = threadIdx.x & 63;
  int t = blockIdx.x * 4 + wv;
  const float* xr = x + (size_t)t * HDIM;
  float4v xv[4];
  float lg[NEXP];
#pragma unroll
  for (int e = 0; e < NEXP; e++) lg[e] = 0.f;
#pragma unroll
  for (int p = 0; p < 4; p++) {
    xv[p] = *(const float4v*)(xr + p * 256 + lane * 4);
#pragma unroll
    for (int c = 0; c < 4; c++) {
      int h = p * 256 + lane * 4 + c;
      float4v g0 = *(const float4v*)(gw + (size_t)h * NEXP);
      float4v g1 = *(const float4v*)(gw + (size_t)h * NEXP + 4);
      float xc = xv[p][c];
      lg[0] += xc * g0[0]; lg[1] += xc * g0[1];
      lg[2] += xc * g0[2]; lg[3] += xc * g0[3];
      lg[4] += xc * g1[0]; lg[5] += xc * g1[1];
      lg[6] += xc * g1[2]; lg[7] += xc * g1[3];
    }
  }
#pragma unroll
  for (int ofs = 1; ofs < 64; ofs <<= 1) {
#pragma unroll
    for (int e = 0; e < NEXP; e++) lg[e] += __shfl_xor(lg[e], ofs, 64);
  }
  int be = 0;
  float bv = lg[0];
#pragma unroll
  for (int e = 1; e < NEXP; e++) {
    if (lg[e] > bv) { bv = lg[e]; be = e; }
  }
  float score = 1.f / (1.f + __expf(-bv));
  if (lane == 0) {
    expert_id[t] = be;
    slot[t] = atomicAdd(&counts[be], 1);
  }
#pragma unroll
  for (int p = 0; p < 4; p++) {
    short4v b, bs;
#pragma unroll
    for (int c = 0; c < 4; c++) {
      b[c] = f2bf(xv[p][c]);
      bs[c] = f2bf(xv[p][c] * score);
    }
    *(short4v*)(xbf + (size_t)t * HDIM + p * 256 + lane * 4) = b;
    *(short4v*)(xsbf + (size_t)t * HDIM + p * 256 + lane * 4) = bs;
  }
}

__global__ void prefix_kernel(const int* __restrict__ counts, int* __restrict__ pad_off) {
  if (threadIdx.x == 0 && blockIdx.x == 0) {
    int run = 0;
    for (int e = 0; e < NEXP; e++) {
      pad_off[e] = run;
      run += (counts[e] + BM - 1) & ~(BM - 1);
    }
    pad_off[NEXP] = run;
  }
}

__global__ __launch_bounds__(256) void build_perm(
    const int* __restrict__ expert_id, const int* __restrict__ slot,
    const int* __restrict__ pad_off, int* __restrict__ perm) {
  int t = blockIdx.x * 256 + threadIdx.x;
  int e = expert_id[t];
  perm[pad_off[e] + slot[t]] = t;
}

// ---------------------------------------------------------------- weight transpose+convert
// merged: z<9 -> w1 (gate+up, 2 passes), z>=9 -> w2 (down). One launch, one tail.
// src fp32 [R][C] -> dst bf16 [C][R]; 64x64 tiles, LDS-staged.

__global__ __launch_bounds__(256) void transpose_all(
    const float* __restrict__ shg, const float* __restrict__ shu,
    const float* __restrict__ rtg, const float* __restrict__ rtu,
    short* __restrict__ shg_t, short* __restrict__ shu_t,
    short* __restrict__ rtg_t, short* __restrict__ rtu_t,
    const float* __restrict__ shd, const float* __restrict__ rtd,
    short* __restrict__ shd_t, short* __restrict__ rtd_t) {
  __shared__ __align__(16) short t[64][66];
  int zz = blockIdx.z;
  int tid = threadIdx.x;
  int tr = tid >> 4, tc = (tid & 15) * 4;
  int oc = tid >> 2, rs = (tid & 3) * 16;
  if (zz < 9) {
    // w1: R=HDIM, C=IDIM; r-tile = blockIdx.y (16), c-tile = blockIdx.x (32)
    const float *s0, *s1;
    short *d0, *d1;
    if (zz == 0) { s0 = shg; s1 = shu; d0 = shg_t; d1 = shu_t; }
    else {
      size_t o = (size_t)(zz - 1) * HDIM * IDIM;
      s0 = rtg + o; s1 = rtu + o; d0 = rtg_t + o; d1 = rtu_t + o;
    }
    const int R = HDIM, C = IDIM;
    int r0 = blockIdx.y * 64, c0 = blockIdx.x * 64;
#pragma unroll
    for (int pass = 0; pass < 2; pass++) {
      const float* s = pass ? s1 : s0;
      short* d = pass ? d1 : d0;
      if (pass) __syncthreads();
#pragma unroll
      for (int i = 0; i < 4; i++) {
        float4v v = *(const float4v*)(s + (size_t)(r0 + tr + i * 16) * C + c0 + tc);
        int w0 = (int)(unsigned short)f2bf(v[0]) | ((int)f2bf(v[1]) << 16);
        int w1 = (int)(unsigned short)f2bf(v[2]) | ((int)f2bf(v[3]) << 16);
        int* p = (int*)&t[tr + i * 16][tc];
        p[0] = w0;
        p[1] = w1;
      }
      __syncthreads();
      short8 o0, o1;
#pragma unroll
      for (int j = 0; j < 8; j++) { o0[j] = t[rs + j][oc]; o1[j] = t[rs + 8 + j][oc]; }
      short* dp = d + (size_t)(c0 + oc) * R + r0 + rs;
      *(short8*)dp = o0;
      *(short8*)(dp + 8) = o1;
    }
  } else {
    // w2: R=IDIM, C=HDIM; r-tile = blockIdx.x (32), c-tile = blockIdx.y (16)
    int z = zz - 9;
    const float* s = (z == 0) ? shd : rtd + (size_t)(z - 1) * IDIM * HDIM;
    short* d = (z == 0) ? shd_t : rtd_t + (size_t)(z - 1) * IDIM * HDIM;
    const int R = IDIM, C = HDIM;
    int r0 = blockIdx.x * 64, c0 = blockIdx.y * 64;
#pragma unroll
    for (int i = 0; i < 4; i++) {
      float4v v = *(const float4v*)(s + (size_t)(r0 + tr + i * 16) * C + c0 + tc);
      int w0 = (int)(unsigned short)f2bf(v[0]) | ((int)f2bf(v[1]) << 16);
      int w1 = (int)(unsigned short)f2bf(v[2]) | ((int)f2bf(v[3]) << 16);
      int* p = (int*)&t[tr + i * 16][tc];
      p[0] = w0;
      p[1] = w1;
    }
    __syncthreads();
    short8 o0, o1;
#pragma unroll
    for (int j = 0; j < 8; j++) { o0[j] = t[rs + j][oc]; o1[j] = t[rs + 8 + j][oc]; }
    short* dp = d + (size_t)(c0 + oc) * R + r0 + rs;
    *(short8*)dp = o0;
    *(short8*)(dp + 8) = o1;
  }
}

// ---------------------------------------------------------------- gemm1: act = silu(A Wg) * (A Wu)
// A bf16 [rows][1024]; B^T bf16 [2048 n][1024 k]. Double-buffered prefetch
// (T3-minimum): ONE barrier per K-step; next-tile global_load_lds issued right
// after the barrier so it flies under this step's ds_read+MFMA and is drained
// by the NEXT iteration's __syncthreads (vmcnt(0)). LDS 2x24KB = 48KB.
// grid y: [0,16) shared tiles, [16,40) routed padded tiles.

__global__ __launch_bounds__(256) void gemm1_swiglu(
    const short* __restrict__ xbf, const short* __restrict__ xsbf,
    const short* __restrict__ shg_t, const short* __restrict__ shu_t,
    const short* __restrict__ rtg_t, const short* __restrict__ rtu_t,
    short* __restrict__ act_sh, short* __restrict__ act_rt,
    const int* __restrict__ pad_off, const int* __restrict__ perm) {
  __shared__ __align__(1024) short sA[2][BM * BK1];
  __shared__ __align__(1024) short sBg[2][BM * BK1];
  __shared__ __align__(1024) short sBu[2][BM * BK1];
  int tid = threadIdx.x, lane = tid & 63, wv = tid >> 6;
  int C0 = blockIdx.x * 128;
  int y = blockIdx.y;
  const short *A, *Bg, *Bu;
  short* act;
  int R0;
  bool routed = (y >= SH_TILES);
  if (!routed) {
    A = xbf; Bg = shg_t; Bu = shu_t; act = act_sh; R0 = y * BM;
  } else {
    R0 = (y - SH_TILES) * BM;
    if (R0 >= pad_off[NEXP]) return;
    int e = 0;
    while (pad_off[e + 1] <= R0) e++;
    size_t o = (size_t)e * HDIM * IDIM;
    A = xsbf; Bg = rtg_t + o; Bu = rtu_t + o; act = act_rt;
  }
  // staging addresses: phys chunk p in {tid, tid+256}, global chunk c = swz(p)
  int c0 = swz(tid), c1 = swz(tid + 256);
  int r0c = c0 >> 2, r1c = c1 >> 2;
  int ar0 = routed ? perm[R0 + r0c] : R0 + r0c;
  int ar1 = routed ? perm[R0 + r1c] : R0 + r1c;
  size_t gA0 = (size_t)ar0 * HDIM + (c0 & 3) * 8;
  size_t gA1 = (size_t)ar1 * HDIM + (c1 & 3) * 8;
  size_t gB0 = (size_t)(C0 + r0c) * HDIM + (c0 & 3) * 8;
  size_t gB1 = (size_t)(C0 + r1c) * HDIM + (c1 & 3) * 8;

  float4v accg[4][4], accu[4][4];
  float4v z4 = {0.f, 0.f, 0.f, 0.f};
#pragma unroll
  for (int i = 0; i < 4; i++)
#pragma unroll
    for (int j = 0; j < 4; j++) { accg[i][j] = z4; accu[i][j] = z4; }

  const int wrow = (wv >> 1) * 64, wcol = (wv & 1) * 64;
  const int mrow = lane & 15, h4 = lane >> 4;
  int aoff[4], boff[4];
#pragma unroll
  for (int i = 0; i < 4; i++)
    aoff[i] = swz(((wrow + i * 16 + mrow) << 2) + h4) * 8;
#pragma unroll
  for (int j = 0; j < 4; j++)
    boff[j] = swz(((wcol + j * 16 + mrow) << 2) + h4) * 8;

  // prologue: stage k0=0 into buffer 0
  gload_lds16(A + gA0, sA[0] + tid * 8);
  gload_lds16(A + gA1, sA[0] + (tid + 256) * 8);
  gload_lds16(Bg + gB0, sBg[0] + tid * 8);
  gload_lds16(Bg + gB1, sBg[0] + (tid + 256) * 8);
  gload_lds16(Bu + gB0, sBu[0] + tid * 8);
  gload_lds16(Bu + gB1, sBu[0] + (tid + 256) * 8);

  int cur = 0;
  for (int k0 = 0; k0 < HDIM; k0 += BK1) {
    __syncthreads();  // drains buf[cur] staging (vmcnt) + prior reads (lgkm)
    int kn = k0 + BK1;
    if (kn < HDIM) {
      short* nA = sA[cur ^ 1];
      short* nG = sBg[cur ^ 1];
      short* nU = sBu[cur ^ 1];
      gload_lds16(A + gA0 + kn, nA + tid * 8);
      gload_lds16(A + gA1 + kn, nA + (tid + 256) * 8);
      gload_lds16(Bg + gB0 + kn, nG + tid * 8);
      gload_lds16(Bg + gB1 + kn, nG + (tid + 256) * 8);
      gload_lds16(Bu + gB0 + kn, nU + tid * 8);
      gload_lds16(Bu + gB1 + kn, nU + (tid + 256) * 8);
    }
    const short* cA = sA[cur];
    const short* cG = sBg[cur];
    const short* cU = sBu[cur];
    short8 af[4], bg[4], bu[4];
#pragma unroll
    for (int i = 0; i < 4; i++) af[i] = *(const short8*)(cA + aoff[i]);
#pragma unroll
    for (int j = 0; j < 4; j++) {
      bg[j] = *(const short8*)(cG + boff[j]);
      bu[j] = *(const short8*)(cU + boff[j]);
    }
#pragma unroll
    for (int i = 0; i < 4; i++)
#pragma unroll
      for (int j = 0; j < 4; j++) {
        accg[i][j] = __builtin_amdgcn_mfma_f32_16x16x32_bf16(af[i], bg[j], accg[i][j], 0, 0, 0);
        accu[i][j] = __builtin_amdgcn_mfma_f32_16x16x32_bf16(af[i], bu[j], accu[i][j], 0, 0, 0);
      }
    cur ^= 1;
  }
  int qrow = h4 * 4, col = mrow;
#pragma unroll
  for (int i = 0; i < 4; i++)
#pragma unroll
    for (int j = 0; j < 4; j++)
#pragma unroll
      for (int r = 0; r < 4; r++) {
        int row = R0 + wrow + i * 16 + qrow + r;
        int c = C0 + wcol + j * 16 + col;
        float g = accg[i][j][r], u = accu[i][j][r];
        float sv = g / (1.f + __expf(-g)) * u;
        act[(size_t)row * IDIM + c] = f2bf(sv);
      }
}

// ---------------------------------------------------------------- gemm2: out = act Wd^T-form
// A bf16 [rows][2048]; B^T bf16 [1024 n][2048 k]. BK=64 (16 MFMA/barrier/wave)
// + same double-buffered prefetch. LDS 2x(16+8)KB = 48KB.
// shared tiles -> plain store to out; routed -> scatter to rt_out; add kernel combines.

__global__ __launch_bounds__(256) void gemm2_down(
    const short* __restrict__ act_sh, const short* __restrict__ act_rt,
    const short* __restrict__ shd_t, const short* __restrict__ rtd_t,
    float* __restrict__ out, float* __restrict__ rt_out,
    const int* __restrict__ pad_off, const int* __restrict__ counts,
    const int* __restrict__ perm) {
  __shared__ __align__(1024) short sA[2][BM * BK2];
  __shared__ __align__(1024) short sB[2][BN2 * BK2];
  int tid = threadIdx.x, lane = tid & 63, wv = tid >> 6;
  int C0 = blockIdx.x * BN2;
  int y = blockIdx.y;
  const short *A, *Bd;
  int R0, e = 0;
  bool routed = (y >= SH_TILES);
  if (!routed) {
    A = act_sh; Bd = shd_t; R0 = y * BM;
  } else {
    R0 = (y - SH_TILES) * BM;
    if (R0 >= pad_off[NEXP]) return;
    while (pad_off[e + 1] <= R0) e++;
    A = act_rt; Bd = rtd_t + (size_t)e * IDIM * HDIM;
  }
  // A tile 128x64 = 1024 chunks (4/thread); B tile 64x64 = 512 chunks (2/thread)
  size_t gA[4], gB[2];
#pragma unroll
  for (int q = 0; q < 4; q++) {
    int c = swz64(tid + 256 * q);
    gA[q] = (size_t)(R0 + (c >> 3)) * IDIM + (c & 7) * 8;
  }
#pragma unroll
  for (int q = 0; q < 2; q++) {
    int c = swz64(tid + 256 * q);
    gB[q] = (size_t)(C0 + (c >> 3)) * IDIM + (c & 7) * 8;
  }

  float4v acc[2][4];
  float4v z4 = {0.f, 0.f, 0.f, 0.f};
#pragma unroll
  for (int i = 0; i < 2; i++)
#pragma unroll
    for (int j = 0; j < 4; j++) acc[i][j] = z4;

  const int wrow = wv * 32;
  const int mrow = lane & 15, h4 = lane >> 4;
  int aoff[2][2], boff[4][2];
#pragma unroll
  for (int i = 0; i < 2; i++)
#pragma unroll
    for (int ks = 0; ks < 2; ks++)
      aoff[i][ks] = swz64(((wrow + i * 16 + mrow) << 3) + ks * 4 + h4) * 8;
#pragma unroll
  for (int j = 0; j < 4; j++)
#pragma unroll
    for (int ks = 0; ks < 2; ks++)
      boff[j][ks] = swz64(((j * 16 + mrow) << 3) + ks * 4 + h4) * 8;

  // prologue: stage k0=0 into buffer 0
#pragma unroll
  for (int q = 0; q < 4; q++) gload_lds16(A + gA[q], sA[0] + (tid + 256 * q) * 8);
#pragma unroll
  for (int q = 0; q < 2; q++) gload_lds16(Bd + gB[q], sB[0] + (tid + 256 * q) * 8);

  int cur = 0;
  for (int k0 = 0; k0 < IDIM; k0 += BK2) {
    __syncthreads();
    int kn = k0 + BK2;
    if (kn < IDIM) {
      short* nA = sA[cur ^ 1];
      short* nB = sB[cur ^ 1];
#pragma unroll
      for (int q = 0; q < 4; q++) gload_lds16(A + gA[q] + kn, nA + (tid + 256 * q) * 8);
#pragma unroll
      for (int q = 0; q < 2; q++) gload_lds16(Bd + gB[q] + kn, nB + (tid + 256 * q) * 8);
    }
    const short* cA = sA[cur];
    const short* cB = sB[cur];
#pragma unroll
    for (int ks = 0; ks < 2; ks++) {
      short8 af[2], bf4[4];
#pragma unroll
      for (int i = 0; i < 2; i++) af[i] = *(const short8*)(cA + aoff[i][ks]);
#pragma unroll
      for (int j = 0; j < 4; j++) bf4[j] = *(const short8*)(cB + boff[j][ks]);
#pragma unroll
      for (int i = 0; i < 2; i++)
#pragma unroll
        for (int j = 0; j < 4; j++)
          acc[i][j] = __builtin_amdgcn_mfma_f32_16x16x32_bf16(af[i], bf4[j], acc[i][j], 0, 0, 0);
    }
    cur ^= 1;
  }
  int qrow = h4 * 4, col = mrow;
#pragma unroll
  for (int i = 0; i < 2; i++)
#pragma unroll
    for (int j = 0; j < 4; j++)
#pragma unroll
      for (int r = 0; r < 4; r++) {
        int row = R0 + wrow + i * 16 + qrow + r;
        int c = C0 + j * 16 + col;
        float v = acc[i][j][r];
        if (!routed) {
          out[(size_t)row * HDIM + c] = v;
        } else if (row - pad_off[e] < counts[e]) {
          rt_out[(size_t)perm[row] * HDIM + c] = v;
        }
      }
}

__global__ __launch_bounds__(256) void add_routed(float* __restrict__ out,
                                                  const float* __restrict__ rt_out) {
  size_t i = ((size_t)blockIdx.x * 256 + threadIdx.x) * 4;
  float4v a = *(const float4v*)(out + i);
  float4v b = *(const float4v*)(rt_out + i);
  a[0] += b[0]; a[1] += b[1]; a[2] += b[2]; a[3] += b[3];
  *(float4v*)(out + i) = a;
}

// ---------------------------------------------------------------- launch

extern "C" void kernel_launch(void* const* d_in, const int* in_sizes, int n_in,
                              void* d_out, int out_size, void* d_ws, size_t ws_size,
                              hipStream_t stream) {
  const float* x       = (const float*)d_in[0];
  const float* gate_w  = (const float*)d_in[1];
  const float* sh_gate = (const float*)d_in[2];
  const float* sh_up   = (const float*)d_in[3];
  const float* sh_down = (const float*)d_in[4];
  const float* rt_gate = (const float*)d_in[5];
  const float* rt_up   = (const float*)d_in[6];
  const float* rt_down = (const float*)d_in[7];
  float* out = (float*)d_out;

  char* w = (char*)d_ws;
  const size_t MB = 1024 * 1024;
  short* xbf    = (short*)(w + 0 * MB);    // 4 MB  [2048][1024] bf16
  short* xsbf   = (short*)(w + 4 * MB);    // 4 MB
  short* act_sh = (short*)(w + 8 * MB);    // 8 MB  [2048][2048]
  short* act_rt = (short*)(w + 16 * MB);   // 12 MB [3072][2048]
  float* rt_out = (float*)(w + 28 * MB);   // 8 MB  [2048][1024] fp32
  short* shg_t  = (short*)(w + 36 * MB);   // 4 MB  [2048][1024]
  short* shu_t  = (short*)(w + 40 * MB);   // 4 MB
  short* shd_t  = (short*)(w + 44 * MB);   // 4 MB  [1024][2048]
  short* rtg_t  = (short*)(w + 48 * MB);   // 32 MB [8][2048][1024]
  short* rtu_t  = (short*)(w + 80 * MB);   // 32 MB
  short* rtd_t  = (short*)(w + 112 * MB);  // 32 MB [8][1024][2048]
  int* ints     = (int*)(w + 144 * MB);
  int* counts    = ints;
  int* pad_off   = ints + 8;
  int* expert_id = ints + 32;
  int* slot      = ints + 32 + 2048;
  int* perm      = ints + 32 + 4096;

  zero_init<<<1, 256, 0, stream>>>(counts, perm);
  router_kernel<<<T_TOK / 4, 256, 0, stream>>>(x, gate_w, xbf, xsbf, expert_id, slot, counts);
  prefix_kernel<<<1, 64, 0, stream>>>(counts, pad_off);
  build_perm<<<T_TOK / 256, 256, 0, stream>>>(expert_id, slot, pad_off, perm);

  transpose_all<<<dim3(32, 16, 18), 256, 0, stream>>>(
      sh_gate, sh_up, rt_gate, rt_up, shg_t, shu_t, rtg_t, rtu_t,
      sh_down, rt_down, shd_t, rtd_t);

  gemm1_swiglu<<<dim3(IDIM / 128, SH_TILES + RT_TILES), 256, 0, stream>>>(
      xbf, xsbf, shg_t, shu_t, rtg_t, rtu_t, act_sh, act_rt, pad_off, perm);

  gemm2_down<<<dim3(HDIM / BN2, SH_TILES + RT_TILES), 256, 0, stream>>>(
      act_sh, act_rt, shd_t, rtd_t, out, rt_out, pad_off, counts, perm);

  add_routed<<<(T_TOK * HDIM) / (256 * 4), 256, 0, stream>>>(out, rt_out);
}

// Round 2
// 401.234 us; speedup vs baseline: 1.0569x; 1.0569x over previous
//
#include <hip/hip_runtime.h>
#include <cstdint>
#include <cstddef>

// B=2,S=1024 -> T=2048 tokens
#define T_TOK 2048
#define HDIM  1024
#define IDIM  2048
#define NEXP  8

#define BM 128
#define BK1 32          // gemm1 K-tile
#define BK2 32          // gemm2 K-tile
#define BN2 64          // gemm2 col tile
#define MAXPAD 3072
#define SH_TILES 16     // T_TOK/BM
#define RT_TILES 24     // MAXPAD/BM

typedef __attribute__((ext_vector_type(8))) short short8;
typedef __attribute__((ext_vector_type(4))) short short4v;
typedef __attribute__((ext_vector_type(4))) float float4v;

__device__ __forceinline__ short f2bf(float f) {
  uint32_t u = __float_as_uint(f);
  u += 0x7fffu + ((u >> 16) & 1u);
  return (short)(u >> 16);
}

__device__ __forceinline__ void gload_lds16(const void* g, void* l) {
  __builtin_amdgcn_global_load_lds(
      (const __attribute__((address_space(1))) uint32_t*)g,
      (__attribute__((address_space(3))) uint32_t*)l, 16, 0, 0);
}

// 16B-chunk XOR swizzle (self-inverse): bits[1:0] ^= bits[5:4].
// Staged with linear LDS dest + swizzled global source; fragment reads apply
// the same swizzle (rule #21). Valid for tiles up to 128 rows x 4 chunks.
__device__ __forceinline__ int swz(int c) { return c ^ ((c >> 4) & 3); }

// ---------------------------------------------------------------- small kernels

__global__ __launch_bounds__(256) void zero_init(int* __restrict__ counts,
                                                 int* __restrict__ perm) {
  int i = threadIdx.x;
  if (i < NEXP) counts[i] = 0;
  for (int p = i; p < MAXPAD; p += 256) perm[p] = 0;
}

// one wave per token: fp32 logits (exact argmax vs ref), score, bf16 copies
__global__ __launch_bounds__(256) void router_kernel(
    const float* __restrict__ x, const float* __restrict__ gw,
    short* __restrict__ xbf, short* __restrict__ xsbf,
    int* __restrict__ expert_id, int* __restrict__ slot,
    int* __restrict__ counts) {
  int wv = threadIdx.x >> 6, lane = threadIdx.x & 63;
  int t = blockIdx.x * 4 + wv;
  const float* xr = x + (size_t)t * HDIM;
  float4v xv[4];
  float lg[NEXP];
#pragma unroll
  for (int e = 0; e < NEXP; e++) lg[e] = 0.f;
#pragma unroll
  for (int p = 0; p < 4; p++) {
    xv[p] = *(const float4v*)(xr + p * 256 + lane * 4);
#pragma unroll
    for (int c = 0; c < 4; c++) {
      int h = p * 256 + lane * 4 + c;
      float4v g0 = *(const float4v*)(gw + (size_t)h * NEXP);
      float4v g1 = *(const float4v*)(gw + (size_t)h * NEXP + 4);
      float xc = xv[p][c];
      lg[0] += xc * g0[0]; lg[1] += xc * g0[1];
      lg[2] += xc * g0[2]; lg[3] += xc * g0[3];
      lg[4] += xc * g1[0]; lg[5] += xc * g1[1];
      lg[6] += xc * g1[2]; lg[7] += xc * g1[3];
    }
  }
#pragma unroll
  for (int ofs = 1; ofs < 64; ofs <<= 1) {
#pragma unroll
    for (int e = 0; e < NEXP; e++) lg[e] += __shfl_xor(lg[e], ofs, 64);
  }
  int be = 0;
  float bv = lg[0];
#pragma unroll
  for (int e = 1; e < NEXP; e++) {
    if (lg[e] > bv) { bv = lg[e]; be = e; }
  }
  float score = 1.f / (1.f + __expf(-bv));
  if (lane == 0) {
    expert_id[t] = be;
    slot[t] = atomicAdd(&counts[be], 1);
  }
#pragma unroll
  for (int p = 0; p < 4; p++) {
    short4v b, bs;
#pragma unroll
    for (int c = 0; c < 4; c++) {
      b[c] = f2bf(xv[p][c]);
      bs[c] = f2bf(xv[p][c] * score);
    }
    *(short4v*)(xbf + (size_t)t * HDIM + p * 256 + lane * 4) = b;
    *(short4v*)(xsbf + (size_t)t * HDIM + p * 256 + lane * 4) = bs;
  }
}

__global__ void prefix_kernel(const int* __restrict__ counts, int* __restrict__ pad_off) {
  if (threadIdx.x == 0 && blockIdx.x == 0) {
    int run = 0;
    for (int e = 0; e < NEXP; e++) {
      pad_off[e] = run;
      run += (counts[e] + BM - 1) & ~(BM - 1);
    }
    pad_off[NEXP] = run;
  }
}

__global__ __launch_bounds__(256) void build_perm(
    const int* __restrict__ expert_id, const int* __restrict__ slot,
    const int* __restrict__ pad_off, int* __restrict__ perm) {
  int t = blockIdx.x * 256 + threadIdx.x;
  int e = expert_id[t];
  perm[pad_off[e] + slot[t]] = t;
}

// ---------------------------------------------------------------- weight transpose+convert
// merged: z<9 -> w1 (gate+up, 2 passes), z>=9 -> w2 (down). One launch, one tail.
// src fp32 [R][C] -> dst bf16 [C][R]; 64x64 tiles, LDS-staged.

__global__ __launch_bounds__(256) void transpose_all(
    const float* __restrict__ shg, const float* __restrict__ shu,
    const float* __restrict__ rtg, const float* __restrict__ rtu,
    short* __restrict__ shg_t, short* __restrict__ shu_t,
    short* __restrict__ rtg_t, short* __restrict__ rtu_t,
    const float* __restrict__ shd, const float* __restrict__ rtd,
    short* __restrict__ shd_t, short* __restrict__ rtd_t) {
  __shared__ __align__(16) short t[64][66];
  int zz = blockIdx.z;
  int tid = threadIdx.x;
  int tr = tid >> 4, tc = (tid & 15) * 4;
  int oc = tid >> 2, rs = (tid & 3) * 16;
  if (zz < 9) {
    // w1: R=HDIM, C=IDIM; r-tile = blockIdx.y (16), c-tile = blockIdx.x (32)
    const float *s0, *s1;
    short *d0, *d1;
    if (zz == 0) { s0 = shg; s1 = shu; d0 = shg_t; d1 = shu_t; }
    else {
      size_t o = (size_t)(zz - 1) * HDIM * IDIM;
      s0 = rtg + o; s1 = rtu + o; d0 = rtg_t + o; d1 = rtu_t + o;
    }
    const int R = HDIM, C = IDIM;
    int r0 = blockIdx.y * 64, c0 = blockIdx.x * 64;
#pragma unroll
    for (int pass = 0; pass < 2; pass++) {
      const float* s = pass ? s1 : s0;
      short* d = pass ? d1 : d0;
      if (pass) __syncthreads();
#pragma unroll
      for (int i = 0; i < 4; i++) {
        float4v v = *(const float4v*)(s + (size_t)(r0 + tr + i * 16) * C + c0 + tc);
        int w0 = (int)(unsigned short)f2bf(v[0]) | ((int)f2bf(v[1]) << 16);
        int w1 = (int)(unsigned short)f2bf(v[2]) | ((int)f2bf(v[3]) << 16);
        int* p = (int*)&t[tr + i * 16][tc];
        p[0] = w0;
        p[1] = w1;
      }
      __syncthreads();
      short8 o0, o1;
#pragma unroll
      for (int j = 0; j < 8; j++) { o0[j] = t[rs + j][oc]; o1[j] = t[rs + 8 + j][oc]; }
      short* dp = d + (size_t)(c0 + oc) * R + r0 + rs;
      *(short8*)dp = o0;
      *(short8*)(dp + 8) = o1;
    }
  } else {
    // w2: R=IDIM, C=HDIM; r-tile = blockIdx.x (32), c-tile = blockIdx.y (16)
    int z = zz - 9;
    const float* s = (z == 0) ? shd : rtd + (size_t)(z - 1) * IDIM * HDIM;
    short* d = (z == 0) ? shd_t : rtd_t + (size_t)(z - 1) * IDIM * HDIM;
    const int R = IDIM, C = HDIM;
    int r0 = blockIdx.x * 64, c0 = blockIdx.y * 64;
#pragma unroll
    for (int i = 0; i < 4; i++) {
      float4v v = *(const float4v*)(s + (size_t)(r0 + tr + i * 16) * C + c0 + tc);
      int w0 = (int)(unsigned short)f2bf(v[0]) | ((int)f2bf(v[1]) << 16);
      int w1 = (int)(unsigned short)f2bf(v[2]) | ((int)f2bf(v[3]) << 16);
      int* p = (int*)&t[tr + i * 16][tc];
      p[0] = w0;
      p[1] = w1;
    }
    __syncthreads();
    short8 o0, o1;
#pragma unroll
    for (int j = 0; j < 8; j++) { o0[j] = t[rs + j][oc]; o1[j] = t[rs + 8 + j][oc]; }
    short* dp = d + (size_t)(c0 + oc) * R + r0 + rs;
    *(short8*)dp = o0;
    *(short8*)(dp + 8) = o1;
  }
}

// ---------------------------------------------------------------- gemm1: act = silu(A Wg) * (A Wu)
// A bf16 [rows][1024]; B^T bf16 [2048 n][1024 k].
// 512 threads / 8 waves (2x4), wave owns 64x32 -> dual acc = 64 VGPR (was 128:
// that capped occupancy at 1 wave/SIMD). 3-buffer K-pipeline, counted
// vmcnt(3) + raw s_barrier: loads stay 2 K-steps in flight, never drained in
// the loop (T3+T4). One barrier per K-step. setprio around MFMA (T5).
// grid y: [0,16) shared tiles, [16,40) routed padded tiles.

#define G1_STAGE(b, kk) do { \
    gload_lds16(A + gA + (kk), sA[b] + tid * 8);   \
    gload_lds16(Bg + gB + (kk), sBg[b] + tid * 8); \
    gload_lds16(Bu + gB + (kk), sBu[b] + tid * 8); } while (0)

__global__ __launch_bounds__(512, 2) void gemm1_swiglu(
    const short* __restrict__ xbf, const short* __restrict__ xsbf,
    const short* __restrict__ shg_t, const short* __restrict__ shu_t,
    const short* __restrict__ rtg_t, const short* __restrict__ rtu_t,
    short* __restrict__ act_sh, short* __restrict__ act_rt,
    const int* __restrict__ pad_off, const int* __restrict__ perm) {
  __shared__ __align__(1024) short sA[3][BM * BK1];
  __shared__ __align__(1024) short sBg[3][BM * BK1];
  __shared__ __align__(1024) short sBu[3][BM * BK1];
  int tid = threadIdx.x, lane = tid & 63, wv = tid >> 6;
  int C0 = blockIdx.x * 128;
  int y = blockIdx.y;
  const short *A, *Bg, *Bu;
  short* act;
  int R0;
  bool routed = (y >= SH_TILES);
  if (!routed) {
    A = xbf; Bg = shg_t; Bu = shu_t; act = act_sh; R0 = y * BM;
  } else {
    R0 = (y - SH_TILES) * BM;
    if (R0 >= pad_off[NEXP]) return;
    int e = 0;
    while (pad_off[e + 1] <= R0) e++;
    size_t o = (size_t)e * HDIM * IDIM;
    A = xsbf; Bg = rtg_t + o; Bu = rtu_t + o; act = act_rt;
  }
  // staging: tile = 512 chunks of 16B, one chunk per thread per tile.
  // phys chunk = tid, global chunk c = swz(tid), row = c>>2, koff = (c&3)*8.
  int c0 = swz(tid);
  int r0c = c0 >> 2;
  int ar0 = routed ? perm[R0 + r0c] : R0 + r0c;
  size_t gA = (size_t)ar0 * HDIM + (c0 & 3) * 8;
  size_t gB = (size_t)(C0 + r0c) * HDIM + (c0 & 3) * 8;

  float4v accg[4][2], accu[4][2];
  float4v z4 = {0.f, 0.f, 0.f, 0.f};
#pragma unroll
  for (int i = 0; i < 4; i++)
#pragma unroll
    for (int j = 0; j < 2; j++) { accg[i][j] = z4; accu[i][j] = z4; }

  const int wrow = (wv >> 2) * 64, wcol = (wv & 3) * 32;
  const int mrow = lane & 15, h4 = lane >> 4;
  int aoff[4], boff[2];
#pragma unroll
  for (int i = 0; i < 4; i++)
    aoff[i] = swz(((wrow + i * 16 + mrow) << 2) + h4) * 8;
#pragma unroll
  for (int j = 0; j < 2; j++)
    boff[j] = swz(((wcol + j * 16 + mrow) << 2) + h4) * 8;

  // prologue: 2 K-steps in flight
  G1_STAGE(0, 0);
  G1_STAGE(1, BK1);

  int cur = 0;
  for (int k0 = 0; k0 < HDIM; k0 += BK1) {
    if (k0 + BK1 < HDIM) {
      asm volatile("s_waitcnt vmcnt(3)" ::: "memory");   // this step's stage done
    } else {
      asm volatile("s_waitcnt vmcnt(0)" ::: "memory");   // final: drain
    }
    __builtin_amdgcn_s_barrier();
    int k2 = k0 + 2 * BK1;
    if (k2 < HDIM) {
      int nb = cur + 2; if (nb >= 3) nb -= 3;
      G1_STAGE(nb, k2);               // overwrites buf last read at iter-1; safe after barrier
    }
    const short* cA = sA[cur];
    const short* cG = sBg[cur];
    const short* cU = sBu[cur];
    short8 af[4], bg[2], bu[2];
#pragma unroll
    for (int i = 0; i < 4; i++) af[i] = *(const short8*)(cA + aoff[i]);
#pragma unroll
    for (int j = 0; j < 2; j++) {
      bg[j] = *(const short8*)(cG + boff[j]);
      bu[j] = *(const short8*)(cU + boff[j]);
    }
    __builtin_amdgcn_s_setprio(1);
#pragma unroll
    for (int i = 0; i < 4; i++)
#pragma unroll
      for (int j = 0; j < 2; j++) {
        accg[i][j] = __builtin_amdgcn_mfma_f32_16x16x32_bf16(af[i], bg[j], accg[i][j], 0, 0, 0);
        accu[i][j] = __builtin_amdgcn_mfma_f32_16x16x32_bf16(af[i], bu[j], accu[i][j], 0, 0, 0);
      }
    __builtin_amdgcn_s_setprio(0);
    cur = (cur == 2) ? 0 : cur + 1;
  }
  int qrow = h4 * 4, col = mrow;
#pragma unroll
  for (int i = 0; i < 4; i++)
#pragma unroll
    for (int j = 0; j < 2; j++)
#pragma unroll
      for (int r = 0; r < 4; r++) {
        int row = R0 + wrow + i * 16 + qrow + r;
        int c = C0 + wcol + j * 16 + col;
        float g = accg[i][j][r], u = accu[i][j][r];
        float sv = g / (1.f + __expf(-g)) * u;
        act[(size_t)row * IDIM + c] = f2bf(sv);
      }
}

// ---------------------------------------------------------------- gemm2: out = act Wd^T-form
// A bf16 [rows][2048]; B^T bf16 [1024 n][2048 k]. 256 thr / 4 waves, tile
// 128x64, BK=32, same 3-buffer counted-vmcnt pipeline. LDS 36KB +
// launch_bounds(256,4) -> 4 blocks/CU target.
// shared tiles -> plain store to out; routed -> scatter to rt_out; add kernel combines.

#define G2_STAGE(b, kk) do { \
    gload_lds16(A + gA0 + (kk), sA[b] + tid * 8);         \
    gload_lds16(A + gA1 + (kk), sA[b] + (tid + 256) * 8); \
    gload_lds16(Bd + gB0 + (kk), sB[b] + tid * 8); } while (0)

__global__ __launch_bounds__(256, 4) void gemm2_down(
    const short* __restrict__ act_sh, const short* __restrict__ act_rt,
    const short* __restrict__ shd_t, const short* __restrict__ rtd_t,
    float* __restrict__ out, float* __restrict__ rt_out,
    const int* __restrict__ pad_off, const int* __restrict__ counts,
    const int* __restrict__ perm) {
  __shared__ __align__(1024) short sA[3][BM * BK2];
  __shared__ __align__(1024) short sB[3][BN2 * BK2];
  int tid = threadIdx.x, lane = tid & 63, wv = tid >> 6;
  int C0 = blockIdx.x * BN2;
  int y = blockIdx.y;
  const short *A, *Bd;
  int R0, e = 0;
  bool routed = (y >= SH_TILES);
  if (!routed) {
    A = act_sh; Bd = shd_t; R0 = y * BM;
  } else {
    R0 = (y - SH_TILES) * BM;
    if (R0 >= pad_off[NEXP]) return;
    while (pad_off[e + 1] <= R0) e++;
    A = act_rt; Bd = rtd_t + (size_t)e * IDIM * HDIM;
  }
  // A tile 128x32 = 512 chunks (2/thread); B tile 64x32 = 256 chunks (1/thread)
  int cA0 = swz(tid), cA1 = swz(tid + 256), cB = swz(tid);
  size_t gA0 = (size_t)(R0 + (cA0 >> 2)) * IDIM + (cA0 & 3) * 8;
  size_t gA1 = (size_t)(R0 + (cA1 >> 2)) * IDIM + (cA1 & 3) * 8;
  size_t gB0 = (size_t)(C0 + (cB >> 2)) * IDIM + (cB & 3) * 8;

  float4v acc[2][4];
  float4v z4 = {0.f, 0.f, 0.f, 0.f};
#pragma unroll
  for (int i = 0; i < 2; i++)
#pragma unroll
    for (int j = 0; j < 4; j++) acc[i][j] = z4;

  const int wrow = wv * 32;
  const int mrow = lane & 15, h4 = lane >> 4;
  int aoff[2], boff[4];
#pragma unroll
  for (int i = 0; i < 2; i++)
    aoff[i] = swz(((wrow + i * 16 + mrow) << 2) + h4) * 8;
#pragma unroll
  for (int j = 0; j < 4; j++)
    boff[j] = swz(((j * 16 + mrow) << 2) + h4) * 8;

  G2_STAGE(0, 0);
  G2_STAGE(1, BK2);

  int cur = 0;
  for (int k0 = 0; k0 < IDIM; k0 += BK2) {
    if (k0 + BK2 < IDIM) {
      asm volatile("s_waitcnt vmcnt(3)" ::: "memory");
    } else {
      asm volatile("s_waitcnt vmcnt(0)" ::: "memory");
    }
    __builtin_amdgcn_s_barrier();
    int k2 = k0 + 2 * BK2;
    if (k2 < IDIM) {
      int nb = cur + 2; if (nb >= 3) nb -= 3;
      G2_STAGE(nb, k2);
    }
    const short* cAp = sA[cur];
    const short* cBp = sB[cur];
    short8 af[2], bf4[4];
#pragma unroll
    for (int i = 0; i < 2; i++) af[i] = *(const short8*)(cAp + aoff[i]);
#pragma unroll
    for (int j = 0; j < 4; j++) bf4[j] = *(const short8*)(cBp + boff[j]);
    __builtin_amdgcn_s_setprio(1);
#pragma unroll
    for (int i = 0; i < 2; i++)
#pragma unroll
      for (int j = 0; j < 4; j++)
        acc[i][j] = __builtin_amdgcn_mfma_f32_16x16x32_bf16(af[i], bf4[j], acc[i][j], 0, 0, 0);
    __builtin_amdgcn_s_setprio(0);
    cur = (cur == 2) ? 0 : cur + 1;
  }
  int qrow = h4 * 4, col = mrow;
#pragma unroll
  for (int i = 0; i < 2; i++)
#pragma unroll
    for (int j = 0; j < 4; j++)
#pragma unroll
      for (int r = 0; r < 4; r++) {
        int row = R0 + wrow + i * 16 + qrow + r;
        int c = C0 + j * 16 + col;
        float v = acc[i][j][r];
        if (!routed) {
          out[(size_t)row * HDIM + c] = v;
        } else if (row - pad_off[e] < counts[e]) {
          rt_out[(size_t)perm[row] * HDIM + c] = v;
        }
      }
}

__global__ __launch_bounds__(256) void add_routed(float* __restrict__ out,
                                                  const float* __restrict__ rt_out) {
  size_t i = ((size_t)blockIdx.x * 256 + threadIdx.x) * 4;
  float4v a = *(const float4v*)(out + i);
  float4v b = *(const float4v*)(rt_out + i);
  a[0] += b[0]; a[1] += b[1]; a[2] += b[2]; a[3] += b[3];
  *(float4v*)(out + i) = a;
}

// ---------------------------------------------------------------- launch

extern "C" void kernel_launch(void* const* d_in, const int* in_sizes, int n_in,
                              void* d_out, int out_size, void* d_ws, size_t ws_size,
                              hipStream_t stream) {
  const float* x       = (const float*)d_in[0];
  const float* gate_w  = (const float*)d_in[1];
  const float* sh_gate = (const float*)d_in[2];
  const float* sh_up   = (const float*)d_in[3];
  const float* sh_down = (const float*)d_in[4];
  const float* rt_gate = (const float*)d_in[5];
  const float* rt_up   = (const float*)d_in[6];
  const float* rt_down = (const float*)d_in[7];
  float* out = (float*)d_out;

  char* w = (char*)d_ws;
  const size_t MB = 1024 * 1024;
  short* xbf    = (short*)(w + 0 * MB);    // 4 MB  [2048][1024] bf16
  short* xsbf   = (short*)(w + 4 * MB);    // 4 MB
  short* act_sh = (short*)(w + 8 * MB);    // 8 MB  [2048][2048]
  short* act_rt = (short*)(w + 16 * MB);   // 12 MB [3072][2048]
  float* rt_out = (float*)(w + 28 * MB);   // 8 MB  [2048][1024] fp32
  short* shg_t  = (short*)(w + 36 * MB);   // 4 MB  [2048][1024]
  short* shu_t  = (short*)(w + 40 * MB);   // 4 MB
  short* shd_t  = (short*)(w + 44 * MB);   // 4 MB  [1024][2048]
  short* rtg_t  = (short*)(w + 48 * MB);   // 32 MB [8][2048][1024]
  short* rtu_t  = (short*)(w + 80 * MB);   // 32 MB
  short* rtd_t  = (short*)(w + 112 * MB);  // 32 MB [8][1024][2048]
  int* ints     = (int*)(w + 144 * MB);
  int* counts    = ints;
  int* pad_off   = ints + 8;
  int* expert_id = ints + 32;
  int* slot      = ints + 32 + 2048;
  int* perm      = ints + 32 + 4096;

  zero_init<<<1, 256, 0, stream>>>(counts, perm);
  router_kernel<<<T_TOK / 4, 256, 0, stream>>>(x, gate_w, xbf, xsbf, expert_id, slot, counts);
  prefix_kernel<<<1, 64, 0, stream>>>(counts, pad_off);
  build_perm<<<T_TOK / 256, 256, 0, stream>>>(expert_id, slot, pad_off, perm);

  transpose_all<<<dim3(32, 16, 18), 256, 0, stream>>>(
      sh_gate, sh_up, rt_gate, rt_up, shg_t, shu_t, rtg_t, rtu_t,
      sh_down, rt_down, shd_t, rtd_t);

  gemm1_swiglu<<<dim3(IDIM / 128, SH_TILES + RT_TILES), 512, 0, stream>>>(
      xbf, xsbf, shg_t, shu_t, rtg_t, rtu_t, act_sh, act_rt, pad_off, perm);

  gemm2_down<<<dim3(HDIM / BN2, SH_TILES + RT_TILES), 256, 0, stream>>>(
      act_sh, act_rt, shd_t, rtd_t, out, rt_out, pad_off, counts, perm);

  add_routed<<<(T_TOK * HDIM) / (256 * 4), 256, 0, stream>>>(out, rt_out);
}